// Round 9
// baseline (361.121 us; speedup 1.0000x reference)
//
#include <hip/hip_runtime.h>
#include <hip/hip_bf16.h>

#define B_   4
#define C_   256
#define N_   4096   // H*W
#define NH_  4
#define HD_  64
#define G_   32
#define CPG_ 8      // C_/G_
#define EPS_ 1e-5f

typedef __bf16 bf16x8 __attribute__((ext_vector_type(8)));
typedef float  f32x4  __attribute__((ext_vector_type(4)));
typedef unsigned int u32x4 __attribute__((ext_vector_type(4)));

#define EXP2F(x) __builtin_amdgcn_exp2f(x)   // v_exp_f32: D = 2^S0

static __device__ __forceinline__ unsigned int packbf(float a, float b) {
    __bf16 x = (__bf16)a, y = (__bf16)b;
    unsigned short ux = __builtin_bit_cast(unsigned short, x);
    unsigned short uy = __builtin_bit_cast(unsigned short, y);
    return (unsigned int)ux | ((unsigned int)uy << 16);
}

// ---------------- GroupNorm: fp32 [b][c][n] -> normalized bf16 TRANSPOSED [b][n][c]
// one block per (b, group); the group's 8 channels are a contiguous 16B chunk per n.
__global__ __launch_bounds__(256) void gn_kernel(const float* __restrict__ in,
                                                 const float* __restrict__ gw,
                                                 const float* __restrict__ gb,
                                                 __bf16* __restrict__ outT) {
    const int b = blockIdx.x / G_;
    const int g = blockIdx.x % G_;
    const int tid = threadIdx.x;
    const size_t base = ((size_t)b * C_ + g * CPG_) * N_;
    const float4* pv = (const float4*)(in + base);
    const int NC = (CPG_ * N_) / 4;

    float s = 0.f, ss = 0.f;
    for (int i = tid; i < NC; i += 256) {
        float4 v = pv[i];
        s  += v.x + v.y + v.z + v.w;
        ss += v.x * v.x + v.y * v.y + v.z * v.z + v.w * v.w;
    }
    #pragma unroll
    for (int m = 32; m >= 1; m >>= 1) { s += __shfl_xor(s, m); ss += __shfl_xor(ss, m); }
    __shared__ float red[8];
    const int w = tid >> 6;
    if ((tid & 63) == 0) { red[w] = s; red[4 + w] = ss; }
    __syncthreads();
    s  = red[0] + red[1] + red[2] + red[3];
    ss = red[4] + red[5] + red[6] + red[7];
    const float mean = s * (1.f / 32768.f);
    const float var  = ss * (1.f / 32768.f) - mean * mean;
    const float rinv = rsqrtf(var + EPS_);

    // y = v*gamma + beta with gamma = gw*rinv, beta = gb - mean*gamma
    float gamma[8], beta[8];
    #pragma unroll
    for (int c = 0; c < CPG_; c++) {
        gamma[c] = gw[g * CPG_ + c] * rinv;
        beta[c]  = gb[g * CPG_ + c] - mean * gamma[c];
    }
    __bf16* ob = outT + (size_t)b * N_ * C_ + g * CPG_;
    #pragma unroll
    for (int nn = 0; nn < 4; nn++) {
        const int n = tid * 4 + nn * 1024;
        f32x4 vv[8];
        #pragma unroll
        for (int c = 0; c < 8; c++) vv[c] = *(const f32x4*)(in + base + (size_t)c * N_ + n);
        #pragma unroll
        for (int k = 0; k < 4; k++) {
            bf16x8 o;
            #pragma unroll
            for (int c = 0; c < 8; c++) o[c] = (__bf16)(vv[c][k] * gamma[c] + beta[c]);
            *(bf16x8*)(ob + (size_t)(n + k) * C_) = o;
        }
    }
}

// ---------------- conv1x1 GEMM, LDS-free: IN is [b][n][c] bf16 -------------------
// OUT[b][o][n] = sum_c W[o][c] * INt[b][n][c] + bias[o]
// mode 0: bf16 [b][o][n]; mode 1: bf16 [(b*NH+h)][n][d]*prescale; mode 2: fp32 +RES
__global__ __launch_bounds__(256) void gemm_kernel(const float* __restrict__ Wf,
                                                   const float* __restrict__ bias,
                                                   const __bf16* __restrict__ INt,
                                                   __bf16* __restrict__ OUTb,
                                                   float* __restrict__ OUTf,
                                                   const float* __restrict__ RES,
                                                   int mode, float prescale) {
    const int n0 = blockIdx.x * 64;
    const int m0 = blockIdx.y * 64;
    const int b  = blockIdx.z;
    const int tid = threadIdx.x;
    const int w = tid >> 6, lane = tid & 63, quad = lane >> 4, l16 = lane & 15;

    const __bf16* inb = INt + (size_t)b * N_ * C_;
    f32x4 acc[4];
    #pragma unroll
    for (int j = 0; j < 4; j++) acc[j] = (f32x4){0.f, 0.f, 0.f, 0.f};

    const int arow = m0 + w * 16 + l16;
    const float* wrow = Wf + (size_t)arow * C_;
    #pragma unroll
    for (int kc = 0; kc < C_; kc += 32) {
        f32x4 w0 = *(const f32x4*)(wrow + kc + quad * 8);
        f32x4 w1 = *(const f32x4*)(wrow + kc + quad * 8 + 4);
        bf16x8 a;
        #pragma unroll
        for (int k = 0; k < 4; k++) { a[k] = (__bf16)w0[k]; a[4 + k] = (__bf16)w1[k]; }
        #pragma unroll
        for (int j = 0; j < 4; j++) {
            bf16x8 bfr = *(const bf16x8*)(inb + (size_t)(n0 + j * 16 + l16) * C_ + kc + quad * 8);
            acc[j] = __builtin_amdgcn_mfma_f32_16x16x32_bf16(a, bfr, acc[j], 0, 0, 0);
        }
    }
    #pragma unroll
    for (int j = 0; j < 4; j++) {
        const int n = n0 + j * 16 + l16;
        #pragma unroll
        for (int r = 0; r < 4; r++) {
            const int o = m0 + w * 16 + quad * 4 + r;
            float v = acc[j][r] + bias[o];
            if (mode == 0) {
                OUTb[(size_t)(b * C_ + o) * N_ + n] = (__bf16)v;
            } else if (mode == 1) {
                const int h = o >> 6, d = o & 63;
                OUTb[((size_t)(b * NH_ + h) * N_ + n) * HD_ + d] = (__bf16)(v * prescale);
            } else {
                v += RES[(size_t)(b * C_ + o) * N_ + n];
                OUTf[(size_t)(b * C_ + o) * N_ + n] = v;
            }
        }
    }
}

// ---------------- Flash attention (R6 structure): 128-q tile, dbuf K/V staging ----
// Rescale-free softmax; output written as [b][n][c] (for the LDS-free o-GEMM).
__global__ __launch_bounds__(256, 2) void attn_kernel(const __bf16* __restrict__ qT,  // [16][N][64], scale*log2e folded
                                                      const __bf16* __restrict__ kT,  // [16][N][64]
                                                      const __bf16* __restrict__ V,   // [4][256][N]
                                                      __bf16* __restrict__ OT) {      // [4][N][256]
    const int flat = blockIdx.y * 32 + blockIdx.x;
    const int bh = flat & 15;          // XCD = flat%8 = bh%8 -> 2 bh per XCD (L2-resident K/V)
    const int qt = flat >> 4;          // 0..31
    const int q0 = qt * 128;
    const int b = bh >> 2, h = bh & 3;
    const int tid = threadIdx.x;
    const int w = tid >> 6, lane = tid & 63, quad = lane >> 4, l16 = lane & 15;

    __shared__ union SMem {
        struct { __bf16 K[2][64][72]; __bf16 Vt[2][64][72]; } kv;   // 36 KB dbuf
        __bf16 Ot[128][72];                                          // epilogue [q][d]
    } sm;

    const __bf16* qTb = qT + (size_t)bh * N_ * HD_;
    const __bf16* kTb = kT + (size_t)bh * N_ * HD_;
    const __bf16* Vb  = V + ((size_t)b * C_ + h * HD_) * N_;

    bf16x8 qa[2][2];
    #pragma unroll
    for (int qg = 0; qg < 2; qg++)
        #pragma unroll
        for (int kk = 0; kk < 2; kk++)
            qa[qg][kk] = *(const bf16x8*)(qTb + (size_t)(q0 + w * 32 + qg * 16 + l16) * HD_ + kk * 32 + quad * 8);

    f32x4 oacc[2][4];
    #pragma unroll
    for (int qg = 0; qg < 2; qg++)
        #pragma unroll
        for (int j = 0; j < 4; j++) oacc[qg][j] = (f32x4){0.f, 0.f, 0.f, 0.f};
    float lsum[2] = {0.f, 0.f};
    const int sl0 = ((quad & 1) * 2) * 16 + l16;
    const int sl1 = sl0 + 16;

    const int srow = tid >> 3;          // 0..31
    const int scol = (tid & 7) * 8;

    bf16x8 rk[2], rv[2];
    #pragma unroll
    for (int i = 0; i < 2; i++) {
        const int row = srow + i * 32;
        rk[i] = *(const bf16x8*)(kTb + (size_t)row * HD_ + scol);
        rv[i] = *(const bf16x8*)(Vb + (size_t)row * N_ + scol);
    }

    for (int it = 0; it < N_ / 64; it++) {
        const int cur = it & 1;
        const int nm0 = ((it + 1) * 64) & (N_ - 1);   // wraps on last (harmless reload)
        #pragma unroll
        for (int i = 0; i < 2; i++) {
            const int row = srow + i * 32;
            *(bf16x8*)(&sm.kv.K[cur][row][scol])  = rk[i];
            *(bf16x8*)(&sm.kv.Vt[cur][row][scol]) = rv[i];
        }
        #pragma unroll
        for (int i = 0; i < 2; i++) {
            const int row = srow + i * 32;
            rk[i] = *(const bf16x8*)(kTb + (size_t)(nm0 + row) * HD_ + scol);
            rv[i] = *(const bf16x8*)(Vb + (size_t)row * N_ + nm0 + scol);
        }
        __syncthreads();
        bf16x8 kb[2][4], vb[2][4];
        #pragma unroll
        for (int kk = 0; kk < 2; kk++)
            #pragma unroll
            for (int j = 0; j < 4; j++) {
                kb[kk][j] = *(const bf16x8*)(&sm.kv.K[cur][j * 16 + l16][kk * 32 + quad * 8]);
                vb[kk][j] = *(const bf16x8*)(&sm.kv.Vt[cur][j * 16 + l16][kk * 32 + quad * 8]);
            }
        #pragma unroll
        for (int qg = 0; qg < 2; qg++) {
            f32x4 s[4];
            #pragma unroll
            for (int j = 0; j < 4; j++) s[j] = (f32x4){0.f, 0.f, 0.f, 0.f};
            #pragma unroll
            for (int kk = 0; kk < 2; kk++)
                #pragma unroll
                for (int j = 0; j < 4; j++)
                    s[j] = __builtin_amdgcn_mfma_f32_16x16x32_bf16(kb[kk][j], qa[qg][kk], s[j], 0, 0, 0);
            float p[4][4];
            float ls = 0.f;
            #pragma unroll
            for (int j = 0; j < 4; j++)
                #pragma unroll
                for (int r = 0; r < 4; r++) { p[j][r] = EXP2F(s[j][r]); ls += p[j][r]; }
            lsum[qg] += ls;
            unsigned int pk0[4], pk1[4];
            #pragma unroll
            for (int j = 0; j < 4; j++) {
                pk0[j] = packbf(p[j][0], p[j][1]);
                pk1[j] = packbf(p[j][2], p[j][3]);
            }
            #pragma unroll
            for (int kk = 0; kk < 2; kk++) {
                unsigned int d0 = 0, d1 = 0, d2 = 0, d3 = 0;
                #pragma unroll
                for (int jj = 0; jj < 2; jj++) {
                    const int j = 2 * kk + jj;
                    unsigned int a0 = (unsigned int)__shfl((int)pk0[j], sl0);
                    unsigned int a1 = (unsigned int)__shfl((int)pk1[j], sl0);
                    unsigned int a2 = (unsigned int)__shfl((int)pk0[j], sl1);
                    unsigned int a3 = (unsigned int)__shfl((int)pk1[j], sl1);
                    if ((quad >> 1) == jj) { d0 = a0; d1 = a1; d2 = a2; d3 = a3; }
                }
                bf16x8 pb = __builtin_bit_cast(bf16x8, (u32x4){d0, d1, d2, d3});
                #pragma unroll
                for (int jd = 0; jd < 4; jd++)
                    oacc[qg][jd] = __builtin_amdgcn_mfma_f32_16x16x32_bf16(vb[kk][jd], pb, oacc[qg][jd], 0, 0, 0);
            }
        }
    }
    // denominators
    float inv[2];
    #pragma unroll
    for (int qg = 0; qg < 2; qg++) {
        float l = lsum[qg];
        l += __shfl_xor(l, 16);
        l += __shfl_xor(l, 32);
        inv[qg] = 1.f / l;
    }
    __syncthreads();   // all kv reads done before Ot overwrites the union
    // stage normalized O as [q][d] in LDS, then write [b][n][c] slice (128B rows)
    #pragma unroll
    for (int qg = 0; qg < 2; qg++)
        #pragma unroll
        for (int jd = 0; jd < 4; jd++)
            #pragma unroll
            for (int r = 0; r < 4; r++)
                sm.Ot[w * 32 + qg * 16 + l16][jd * 16 + quad * 4 + r] = (__bf16)(oacc[qg][jd][r] * inv[qg]);
    __syncthreads();
    __bf16* Ob = OT + ((size_t)b * N_ + q0) * C_ + h * HD_;
    #pragma unroll
    for (int i = 0; i < 4; i++) {
        const int idx = tid + i * 256;          // 1024 chunks of 8 elems
        const int row = idx >> 3, col = (idx & 7) * 8;
        *(bf16x8*)(Ob + (size_t)row * C_ + col) = *(const bf16x8*)(&sm.Ot[row][col]);
    }
}

extern "C" void kernel_launch(void* const* d_in, const int* in_sizes, int n_in,
                              void* d_out, int out_size, void* d_ws, size_t ws_size,
                              hipStream_t stream) {
    const float* x     = (const float*)d_in[0];
    const float* cond  = (const float*)d_in[1];
    const float* gnqw  = (const float*)d_in[2];
    const float* gnqb  = (const float*)d_in[3];
    const float* gnkw  = (const float*)d_in[4];
    const float* gnkb  = (const float*)d_in[5];
    const float* wq    = (const float*)d_in[6];
    const float* bq    = (const float*)d_in[7];
    const float* wk    = (const float*)d_in[8];
    const float* bk    = (const float*)d_in[9];
    const float* wv    = (const float*)d_in[10];
    const float* bv    = (const float*)d_in[11];
    const float* wo    = (const float*)d_in[12];
    const float* bo    = (const float*)d_in[13];
    float* out = (float*)d_out;

    const size_t TEN = (size_t)B_ * C_ * N_;
    __bf16* gnxT   = (__bf16*)d_ws;            // [b][n][c]
    __bf16* gncT   = gnxT + TEN;               // [b][n][c]
    __bf16* qT     = gncT + TEN;               // [bh][n][d]
    __bf16* kT     = qT  + TEN;                // [bh][n][d]
    __bf16* v      = kT  + TEN;                // [b][c][n]
    __bf16* attnoT = v   + TEN;                // [b][n][c]

    gn_kernel<<<dim3(B_ * G_), 256, 0, stream>>>(x,    gnqw, gnqb, gnxT);
    gn_kernel<<<dim3(B_ * G_), 256, 0, stream>>>(cond, gnkw, gnkb, gncT);

    dim3 gg(N_ / 64, C_ / 64, B_);
    gemm_kernel<<<gg, 256, 0, stream>>>(wq, bq, gnxT, qT, nullptr, nullptr, 1, 0.125f * 1.44269504088896f);
    gemm_kernel<<<gg, 256, 0, stream>>>(wk, bk, gncT, kT, nullptr, nullptr, 1, 1.0f);
    gemm_kernel<<<gg, 256, 0, stream>>>(wv, bv, gncT, v,  nullptr, nullptr, 0, 1.0f);

    attn_kernel<<<dim3(32, 16), 256, 0, stream>>>(qT, kT, v, attnoT);

    gemm_kernel<<<gg, 256, 0, stream>>>(wo, bo, attnoT, nullptr, out, x, 2, 1.0f);
}

// Round 10
// 354.752 us; speedup vs baseline: 1.0180x; 1.0180x over previous
//
#include <hip/hip_runtime.h>
#include <hip/hip_bf16.h>

#define B_   4
#define C_   256
#define N_   4096   // H*W
#define NH_  4
#define HD_  64
#define G_   32
#define CPG_ 8      // C_/G_
#define EPS_ 1e-5f

typedef __bf16 bf16x8 __attribute__((ext_vector_type(8)));
typedef float  f32x4  __attribute__((ext_vector_type(4)));
typedef unsigned int u32x4 __attribute__((ext_vector_type(4)));

#define EXP2F(x) __builtin_amdgcn_exp2f(x)   // v_exp_f32: D = 2^S0

static __device__ __forceinline__ unsigned int packbf(float a, float b) {
    __bf16 x = (__bf16)a, y = (__bf16)b;
    unsigned short ux = __builtin_bit_cast(unsigned short, x);
    unsigned short uy = __builtin_bit_cast(unsigned short, y);
    return (unsigned int)ux | ((unsigned int)uy << 16);
}

// ---------------- GN phase 1: per-(tensor,b,group) mean & rinv --------------------
__global__ __launch_bounds__(256) void gn_stats(const float* __restrict__ x,
                                                const float* __restrict__ cond,
                                                float* __restrict__ stats) {
    const int bid = blockIdx.x;                // t*128 + b*32 + g
    const int t = bid >> 7, b = (bid >> 5) & 3, g = bid & 31;
    const int tid = threadIdx.x;
    const float* in = (t ? cond : x) + ((size_t)b * C_ + g * CPG_) * N_;
    const float4* pv = (const float4*)in;
    const int NC = (CPG_ * N_) / 4;            // 8192 chunks

    float s = 0.f, ss = 0.f;
    for (int i = tid; i < NC; i += 256) {
        float4 v = pv[i];
        s  += v.x + v.y + v.z + v.w;
        ss += v.x * v.x + v.y * v.y + v.z * v.z + v.w * v.w;
    }
    #pragma unroll
    for (int m = 32; m >= 1; m >>= 1) { s += __shfl_xor(s, m); ss += __shfl_xor(ss, m); }
    __shared__ float red[8];
    const int w = tid >> 6;
    if ((tid & 63) == 0) { red[w] = s; red[4 + w] = ss; }
    __syncthreads();
    if (tid == 0) {
        s  = red[0] + red[1] + red[2] + red[3];
        ss = red[4] + red[5] + red[6] + red[7];
        const float mean = s * (1.f / 32768.f);
        const float var  = ss * (1.f / 32768.f) - mean * mean;
        stats[bid * 2 + 0] = mean;
        stats[bid * 2 + 1] = rsqrtf(var + EPS_);
    }
}

// ---------------- GN phase 2: normalize + transpose -> bf16 [b][n][c] -------------
// block: (t, b, go(4: 64-c slab), nt(32: 128-n tile)). LDS writes contiguous b128
// (bank-spread); transposed reads scalar u16 with c const per inst, n across lanes
// (bank = 4c + n/2 -> conflict-free). Global writes: 128B per-block-exclusive chunks.
__global__ __launch_bounds__(256) void gn_normT(const float* __restrict__ x,
                                                const float* __restrict__ cond,
                                                const float* __restrict__ gwq,
                                                const float* __restrict__ gbq,
                                                const float* __restrict__ gwk,
                                                const float* __restrict__ gbk,
                                                const float* __restrict__ stats,
                                                __bf16* __restrict__ outq,
                                                __bf16* __restrict__ outk) {
    const int bid = blockIdx.x;                // t*512 + b*128 + go*32 + nt
    const int t = bid >> 9, b = (bid >> 7) & 3, go = (bid >> 5) & 3, nt = bid & 31;
    const int tid = threadIdx.x;
    const float* in = t ? cond : x;
    const float* gw = t ? gwk : gwq;
    const float* gb = t ? gbk : gbq;
    __bf16* out = t ? outk : outq;

    const int cloc = tid >> 2;                 // 0..63
    const int cg = go * 64 + cloc;
    const int gidx = cg >> 3;
    const float mean = stats[((t * 4 + b) * 32 + gidx) * 2 + 0];
    const float rinv = stats[((t * 4 + b) * 32 + gidx) * 2 + 1];
    const float gamma = gw[cg] * rinv;
    const float beta  = gb[cg] - mean * gamma;

    __shared__ __bf16 T[64][72];
    const int nq = (tid & 3) * 16;
    const int n_ = tid & 63, cp = tid >> 6;

    #pragma unroll
    for (int sub = 0; sub < 2; sub++) {
        const int nbase = nt * 128 + sub * 64;
        const float* src = in + ((size_t)b * C_ + cg) * N_ + nbase + nq;
        f32x4 v[4];
        #pragma unroll
        for (int i = 0; i < 4; i++) v[i] = *(const f32x4*)(src + i * 4);
        bf16x8 o0, o1;
        #pragma unroll
        for (int i = 0; i < 4; i++) {
            o0[i]     = (__bf16)(v[0][i] * gamma + beta);
            o0[4 + i] = (__bf16)(v[1][i] * gamma + beta);
            o1[i]     = (__bf16)(v[2][i] * gamma + beta);
            o1[4 + i] = (__bf16)(v[3][i] * gamma + beta);
        }
        if (sub) __syncthreads();              // prior write pass done
        *(bf16x8*)(&T[cloc][nq])     = o0;
        *(bf16x8*)(&T[cloc][nq + 8]) = o1;
        __syncthreads();
        bf16x8 w0, w1;
        #pragma unroll
        for (int i = 0; i < 8; i++) { w0[i] = T[cp * 16 + i][n_]; w1[i] = T[cp * 16 + 8 + i][n_]; }
        __bf16* dst = out + ((size_t)b * N_ + nbase + n_) * C_ + go * 64 + cp * 16;
        *(bf16x8*)dst = w0;
        *(bf16x8*)(dst + 8) = w1;
    }
}

// ---------------- conv1x1 GEMM, LDS-free: IN is [b][n][c] bf16 -------------------
__global__ __launch_bounds__(256) void gemm_kernel(const float* __restrict__ Wf,
                                                   const float* __restrict__ bias,
                                                   const __bf16* __restrict__ INt,
                                                   __bf16* __restrict__ OUTb,
                                                   float* __restrict__ OUTf,
                                                   const float* __restrict__ RES,
                                                   int mode, float prescale) {
    const int n0 = blockIdx.x * 64;
    const int m0 = blockIdx.y * 64;
    const int b  = blockIdx.z;
    const int tid = threadIdx.x;
    const int w = tid >> 6, lane = tid & 63, quad = lane >> 4, l16 = lane & 15;

    const __bf16* inb = INt + (size_t)b * N_ * C_;
    f32x4 acc[4];
    #pragma unroll
    for (int j = 0; j < 4; j++) acc[j] = (f32x4){0.f, 0.f, 0.f, 0.f};

    const int arow = m0 + w * 16 + l16;
    const float* wrow = Wf + (size_t)arow * C_;
    #pragma unroll
    for (int kc = 0; kc < C_; kc += 32) {
        f32x4 w0 = *(const f32x4*)(wrow + kc + quad * 8);
        f32x4 w1 = *(const f32x4*)(wrow + kc + quad * 8 + 4);
        bf16x8 a;
        #pragma unroll
        for (int k = 0; k < 4; k++) { a[k] = (__bf16)w0[k]; a[4 + k] = (__bf16)w1[k]; }
        #pragma unroll
        for (int j = 0; j < 4; j++) {
            bf16x8 bfr = *(const bf16x8*)(inb + (size_t)(n0 + j * 16 + l16) * C_ + kc + quad * 8);
            acc[j] = __builtin_amdgcn_mfma_f32_16x16x32_bf16(a, bfr, acc[j], 0, 0, 0);
        }
    }
    #pragma unroll
    for (int j = 0; j < 4; j++) {
        const int n = n0 + j * 16 + l16;
        #pragma unroll
        for (int r = 0; r < 4; r++) {
            const int o = m0 + w * 16 + quad * 4 + r;
            float v = acc[j][r] + bias[o];
            if (mode == 0) {
                OUTb[(size_t)(b * C_ + o) * N_ + n] = (__bf16)v;
            } else if (mode == 1) {
                const int h = o >> 6, d = o & 63;
                OUTb[((size_t)(b * NH_ + h) * N_ + n) * HD_ + d] = (__bf16)(v * prescale);
            } else {
                v += RES[(size_t)(b * C_ + o) * N_ + n];
                OUTf[(size_t)(b * C_ + o) * N_ + n] = v;
            }
        }
    }
}

// ---------------- Flash attention (R6/R9 structure): 128-q tile, dbuf K/V ---------
__global__ __launch_bounds__(256, 2) void attn_kernel(const __bf16* __restrict__ qT,  // [16][N][64], scale*log2e folded
                                                      const __bf16* __restrict__ kT,  // [16][N][64]
                                                      const __bf16* __restrict__ V,   // [4][256][N]
                                                      __bf16* __restrict__ OT) {      // [4][N][256]
    const int flat = blockIdx.y * 32 + blockIdx.x;
    const int bh = flat & 15;          // XCD = flat%8 = bh%8 -> 2 bh per XCD (L2-resident K/V)
    const int qt = flat >> 4;          // 0..31
    const int q0 = qt * 128;
    const int b = bh >> 2, h = bh & 3;
    const int tid = threadIdx.x;
    const int w = tid >> 6, lane = tid & 63, quad = lane >> 4, l16 = lane & 15;

    __shared__ union SMem {
        struct { __bf16 K[2][64][72]; __bf16 Vt[2][64][72]; } kv;   // 36 KB dbuf
        __bf16 Ot[128][72];                                          // epilogue [q][d]
    } sm;

    const __bf16* qTb = qT + (size_t)bh * N_ * HD_;
    const __bf16* kTb = kT + (size_t)bh * N_ * HD_;
    const __bf16* Vb  = V + ((size_t)b * C_ + h * HD_) * N_;

    bf16x8 qa[2][2];
    #pragma unroll
    for (int qg = 0; qg < 2; qg++)
        #pragma unroll
        for (int kk = 0; kk < 2; kk++)
            qa[qg][kk] = *(const bf16x8*)(qTb + (size_t)(q0 + w * 32 + qg * 16 + l16) * HD_ + kk * 32 + quad * 8);

    f32x4 oacc[2][4];
    #pragma unroll
    for (int qg = 0; qg < 2; qg++)
        #pragma unroll
        for (int j = 0; j < 4; j++) oacc[qg][j] = (f32x4){0.f, 0.f, 0.f, 0.f};
    float lsum[2] = {0.f, 0.f};
    const int sl0 = ((quad & 1) * 2) * 16 + l16;
    const int sl1 = sl0 + 16;

    const int srow = tid >> 3;          // 0..31
    const int scol = (tid & 7) * 8;

    bf16x8 rk[2], rv[2];
    #pragma unroll
    for (int i = 0; i < 2; i++) {
        const int row = srow + i * 32;
        rk[i] = *(const bf16x8*)(kTb + (size_t)row * HD_ + scol);
        rv[i] = *(const bf16x8*)(Vb + (size_t)row * N_ + scol);
    }

    for (int it = 0; it < N_ / 64; it++) {
        const int cur = it & 1;
        const int nm0 = ((it + 1) * 64) & (N_ - 1);   // wraps on last (harmless reload)
        #pragma unroll
        for (int i = 0; i < 2; i++) {
            const int row = srow + i * 32;
            *(bf16x8*)(&sm.kv.K[cur][row][scol])  = rk[i];
            *(bf16x8*)(&sm.kv.Vt[cur][row][scol]) = rv[i];
        }
        #pragma unroll
        for (int i = 0; i < 2; i++) {
            const int row = srow + i * 32;
            rk[i] = *(const bf16x8*)(kTb + (size_t)(nm0 + row) * HD_ + scol);
            rv[i] = *(const bf16x8*)(Vb + (size_t)row * N_ + nm0 + scol);
        }
        __syncthreads();
        bf16x8 kb[2][4], vb[2][4];
        #pragma unroll
        for (int kk = 0; kk < 2; kk++)
            #pragma unroll
            for (int j = 0; j < 4; j++) {
                kb[kk][j] = *(const bf16x8*)(&sm.kv.K[cur][j * 16 + l16][kk * 32 + quad * 8]);
                vb[kk][j] = *(const bf16x8*)(&sm.kv.Vt[cur][j * 16 + l16][kk * 32 + quad * 8]);
            }
        #pragma unroll
        for (int qg = 0; qg < 2; qg++) {
            f32x4 s[4];
            #pragma unroll
            for (int j = 0; j < 4; j++) s[j] = (f32x4){0.f, 0.f, 0.f, 0.f};
            #pragma unroll
            for (int kk = 0; kk < 2; kk++)
                #pragma unroll
                for (int j = 0; j < 4; j++)
                    s[j] = __builtin_amdgcn_mfma_f32_16x16x32_bf16(kb[kk][j], qa[qg][kk], s[j], 0, 0, 0);
            float p[4][4];
            float ls = 0.f;
            #pragma unroll
            for (int j = 0; j < 4; j++)
                #pragma unroll
                for (int r = 0; r < 4; r++) { p[j][r] = EXP2F(s[j][r]); ls += p[j][r]; }
            lsum[qg] += ls;
            unsigned int pk0[4], pk1[4];
            #pragma unroll
            for (int j = 0; j < 4; j++) {
                pk0[j] = packbf(p[j][0], p[j][1]);
                pk1[j] = packbf(p[j][2], p[j][3]);
            }
            #pragma unroll
            for (int kk = 0; kk < 2; kk++) {
                unsigned int d0 = 0, d1 = 0, d2 = 0, d3 = 0;
                #pragma unroll
                for (int jj = 0; jj < 2; jj++) {
                    const int j = 2 * kk + jj;
                    unsigned int a0 = (unsigned int)__shfl((int)pk0[j], sl0);
                    unsigned int a1 = (unsigned int)__shfl((int)pk1[j], sl0);
                    unsigned int a2 = (unsigned int)__shfl((int)pk0[j], sl1);
                    unsigned int a3 = (unsigned int)__shfl((int)pk1[j], sl1);
                    if ((quad >> 1) == jj) { d0 = a0; d1 = a1; d2 = a2; d3 = a3; }
                }
                bf16x8 pb = __builtin_bit_cast(bf16x8, (u32x4){d0, d1, d2, d3});
                #pragma unroll
                for (int jd = 0; jd < 4; jd++)
                    oacc[qg][jd] = __builtin_amdgcn_mfma_f32_16x16x32_bf16(vb[kk][jd], pb, oacc[qg][jd], 0, 0, 0);
            }
        }
    }
    float inv[2];
    #pragma unroll
    for (int qg = 0; qg < 2; qg++) {
        float l = lsum[qg];
        l += __shfl_xor(l, 16);
        l += __shfl_xor(l, 32);
        inv[qg] = 1.f / l;
    }
    __syncthreads();
    #pragma unroll
    for (int qg = 0; qg < 2; qg++)
        #pragma unroll
        for (int jd = 0; jd < 4; jd++)
            #pragma unroll
            for (int r = 0; r < 4; r++)
                sm.Ot[w * 32 + qg * 16 + l16][jd * 16 + quad * 4 + r] = (__bf16)(oacc[qg][jd][r] * inv[qg]);
    __syncthreads();
    __bf16* Ob = OT + ((size_t)b * N_ + q0) * C_ + h * HD_;
    #pragma unroll
    for (int i = 0; i < 4; i++) {
        const int idx = tid + i * 256;
        const int row = idx >> 3, col = (idx & 7) * 8;
        *(bf16x8*)(Ob + (size_t)row * C_ + col) = *(const bf16x8*)(&sm.Ot[row][col]);
    }
}

extern "C" void kernel_launch(void* const* d_in, const int* in_sizes, int n_in,
                              void* d_out, int out_size, void* d_ws, size_t ws_size,
                              hipStream_t stream) {
    const float* x     = (const float*)d_in[0];
    const float* cond  = (const float*)d_in[1];
    const float* gnqw  = (const float*)d_in[2];
    const float* gnqb  = (const float*)d_in[3];
    const float* gnkw  = (const float*)d_in[4];
    const float* gnkb  = (const float*)d_in[5];
    const float* wq    = (const float*)d_in[6];
    const float* bq    = (const float*)d_in[7];
    const float* wk    = (const float*)d_in[8];
    const float* bk    = (const float*)d_in[9];
    const float* wv    = (const float*)d_in[10];
    const float* bv    = (const float*)d_in[11];
    const float* wo    = (const float*)d_in[12];
    const float* bo    = (const float*)d_in[13];
    float* out = (float*)d_out;

    const size_t TEN = (size_t)B_ * C_ * N_;
    __bf16* gnxT   = (__bf16*)d_ws;            // [b][n][c]
    __bf16* gncT   = gnxT + TEN;               // [b][n][c]
    __bf16* qT     = gncT + TEN;               // [bh][n][d]
    __bf16* kT     = qT  + TEN;                // [bh][n][d]
    __bf16* v      = kT  + TEN;                // [b][c][n]
    __bf16* attnoT = v   + TEN;                // [b][n][c]

    // stats (1 KB) parked in qT's space: written by gn_stats, read by gn_normT,
    // then overwritten by the q-GEMM afterwards.
    float* stats = (float*)qT;

    gn_stats<<<dim3(2 * B_ * G_), 256, 0, stream>>>(x, cond, stats);
    gn_normT<<<dim3(1024), 256, 0, stream>>>(x, cond, gnqw, gnqb, gnkw, gnkb,
                                             stats, gnxT, gncT);

    dim3 gg(N_ / 64, C_ / 64, B_);
    gemm_kernel<<<gg, 256, 0, stream>>>(wq, bq, gnxT, qT, nullptr, nullptr, 1, 0.125f * 1.44269504088896f);
    gemm_kernel<<<gg, 256, 0, stream>>>(wk, bk, gncT, kT, nullptr, nullptr, 1, 1.0f);
    gemm_kernel<<<gg, 256, 0, stream>>>(wv, bv, gncT, v,  nullptr, nullptr, 0, 1.0f);

    attn_kernel<<<dim3(32, 16), 256, 0, stream>>>(qT, kT, v, attnoT);

    gemm_kernel<<<gg, 256, 0, stream>>>(wo, bo, attnoT, nullptr, out, x, 2, 1.0f);
}

// Round 11
// 331.613 us; speedup vs baseline: 1.0890x; 1.0698x over previous
//
#include <hip/hip_runtime.h>
#include <hip/hip_bf16.h>

#define B_   4
#define C_   256
#define N_   4096   // H*W
#define NH_  4
#define HD_  64
#define G_   32
#define CPG_ 8      // C_/G_
#define EPS_ 1e-5f

typedef __bf16 bf16x8 __attribute__((ext_vector_type(8)));
typedef float  f32x4  __attribute__((ext_vector_type(4)));
typedef unsigned int u32x4 __attribute__((ext_vector_type(4)));

#define EXP2F(x) __builtin_amdgcn_exp2f(x)   // v_exp_f32: D = 2^S0

static __device__ __forceinline__ unsigned int packbf(float a, float b) {
    __bf16 x = (__bf16)a, y = (__bf16)b;
    unsigned short ux = __builtin_bit_cast(unsigned short, x);
    unsigned short uy = __builtin_bit_cast(unsigned short, y);
    return (unsigned int)ux | ((unsigned int)uy << 16);
}

// ---------------- GN phase 1: per-(tensor,b,group) mean & rinv; 8 waves/block -----
__global__ __launch_bounds__(512) void gn_stats(const float* __restrict__ x,
                                                const float* __restrict__ cond,
                                                float* __restrict__ stats) {
    const int bid = blockIdx.x;                // t*128 + b*32 + g
    const int t = bid >> 7, b = (bid >> 5) & 3, g = bid & 31;
    const int tid = threadIdx.x;
    const float* in = (t ? cond : x) + ((size_t)b * C_ + g * CPG_) * N_;
    const float4* pv = (const float4*)in;
    const int NC = (CPG_ * N_) / 4;            // 8192 chunks

    float s = 0.f, ss = 0.f;
    for (int i = tid; i < NC; i += 512) {
        float4 v = pv[i];
        s  += v.x + v.y + v.z + v.w;
        ss += v.x * v.x + v.y * v.y + v.z * v.z + v.w * v.w;
    }
    #pragma unroll
    for (int m = 32; m >= 1; m >>= 1) { s += __shfl_xor(s, m); ss += __shfl_xor(ss, m); }
    __shared__ float red[16];
    const int w = tid >> 6;
    if ((tid & 63) == 0) { red[w] = s; red[8 + w] = ss; }
    __syncthreads();
    if (tid == 0) {
        s = 0.f; ss = 0.f;
        #pragma unroll
        for (int i = 0; i < 8; i++) { s += red[i]; ss += red[8 + i]; }
        const float mean = s * (1.f / 32768.f);
        const float var  = ss * (1.f / 32768.f) - mean * mean;
        stats[bid * 2 + 0] = mean;
        stats[bid * 2 + 1] = rsqrtf(var + EPS_);
    }
}

// ---------------- GN phase 2: normalize + transpose -> bf16 [b][n][c] (R10 proven) -
__global__ __launch_bounds__(256) void gn_normT(const float* __restrict__ x,
                                                const float* __restrict__ cond,
                                                const float* __restrict__ gwq,
                                                const float* __restrict__ gbq,
                                                const float* __restrict__ gwk,
                                                const float* __restrict__ gbk,
                                                const float* __restrict__ stats,
                                                __bf16* __restrict__ outq,
                                                __bf16* __restrict__ outk) {
    const int bid = blockIdx.x;                // t*512 + b*128 + go*32 + nt
    const int t = bid >> 9, b = (bid >> 7) & 3, go = (bid >> 5) & 3, nt = bid & 31;
    const int tid = threadIdx.x;
    const float* in = t ? cond : x;
    const float* gw = t ? gwk : gwq;
    const float* gb = t ? gbk : gbq;
    __bf16* out = t ? outk : outq;

    const int cloc = tid >> 2;                 // 0..63
    const int cg = go * 64 + cloc;
    const int gidx = cg >> 3;
    const float mean = stats[((t * 4 + b) * 32 + gidx) * 2 + 0];
    const float rinv = stats[((t * 4 + b) * 32 + gidx) * 2 + 1];
    const float gamma = gw[cg] * rinv;
    const float beta  = gb[cg] - mean * gamma;

    __shared__ __bf16 T[64][72];
    const int nq = (tid & 3) * 16;
    const int n_ = tid & 63, cp = tid >> 6;

    #pragma unroll
    for (int sub = 0; sub < 2; sub++) {
        const int nbase = nt * 128 + sub * 64;
        const float* src = in + ((size_t)b * C_ + cg) * N_ + nbase + nq;
        f32x4 v[4];
        #pragma unroll
        for (int i = 0; i < 4; i++) v[i] = *(const f32x4*)(src + i * 4);
        bf16x8 o0, o1;
        #pragma unroll
        for (int i = 0; i < 4; i++) {
            o0[i]     = (__bf16)(v[0][i] * gamma + beta);
            o0[4 + i] = (__bf16)(v[1][i] * gamma + beta);
            o1[i]     = (__bf16)(v[2][i] * gamma + beta);
            o1[4 + i] = (__bf16)(v[3][i] * gamma + beta);
        }
        if (sub) __syncthreads();
        *(bf16x8*)(&T[cloc][nq])     = o0;
        *(bf16x8*)(&T[cloc][nq + 8]) = o1;
        __syncthreads();
        bf16x8 w0, w1;
        #pragma unroll
        for (int i = 0; i < 8; i++) { w0[i] = T[cp * 16 + i][n_]; w1[i] = T[cp * 16 + 8 + i][n_]; }
        __bf16* dst = out + ((size_t)b * N_ + nbase + n_) * C_ + go * 64 + cp * 16;
        *(bf16x8*)dst = w0;
        *(bf16x8*)(dst + 8) = w1;
    }
}

// ---------------- fused q/k/v conv1x1 GEMM, LDS-free, 128n x 64m tiles ------------
// z = tz*4 + b; tz: 0=q (gnxT,wq -> qT*qscale), 1=k (gncT,wk -> kT), 2=v (gncT,wv -> V)
__global__ __launch_bounds__(256) void gemm_qkv(const float* __restrict__ wqf, const float* __restrict__ bqf,
                                                const float* __restrict__ wkf, const float* __restrict__ bkf,
                                                const float* __restrict__ wvf, const float* __restrict__ bvf,
                                                const __bf16* __restrict__ gnxT,
                                                const __bf16* __restrict__ gncT,
                                                __bf16* __restrict__ qT,
                                                __bf16* __restrict__ kT,
                                                __bf16* __restrict__ vO,
                                                float qscale) {
    const int n0 = blockIdx.x * 128;
    const int m0 = blockIdx.y * 64;
    const int z  = blockIdx.z;
    const int tz = z >> 2, b = z & 3;
    const float* Wf   = (tz == 0) ? wqf : (tz == 1) ? wkf : wvf;
    const float* bias = (tz == 0) ? bqf : (tz == 1) ? bkf : bvf;
    const __bf16* inb = ((tz == 0) ? gnxT : gncT) + (size_t)b * N_ * C_;
    const int tid = threadIdx.x;
    const int w = tid >> 6, lane = tid & 63, quad = lane >> 4, l16 = lane & 15;

    f32x4 acc[8];
    #pragma unroll
    for (int j = 0; j < 8; j++) acc[j] = (f32x4){0.f, 0.f, 0.f, 0.f};

    const int arow = m0 + w * 16 + l16;
    const float* wrow = Wf + (size_t)arow * C_;
    #pragma unroll
    for (int kc = 0; kc < C_; kc += 32) {
        f32x4 w0 = *(const f32x4*)(wrow + kc + quad * 8);
        f32x4 w1 = *(const f32x4*)(wrow + kc + quad * 8 + 4);
        bf16x8 a;
        #pragma unroll
        for (int k = 0; k < 4; k++) { a[k] = (__bf16)w0[k]; a[4 + k] = (__bf16)w1[k]; }
        #pragma unroll
        for (int j = 0; j < 8; j++) {
            bf16x8 bfr = *(const bf16x8*)(inb + (size_t)(n0 + j * 16 + l16) * C_ + kc + quad * 8);
            acc[j] = __builtin_amdgcn_mfma_f32_16x16x32_bf16(a, bfr, acc[j], 0, 0, 0);
        }
    }
    const int h = m0 >> 6;                     // q/k: head index (m0 aligned to 64)
    const float sc = (tz == 0) ? qscale : 1.0f;
    #pragma unroll
    for (int j = 0; j < 8; j++) {
        const int n = n0 + j * 16 + l16;
        #pragma unroll
        for (int r = 0; r < 4; r++) {
            const int o = m0 + w * 16 + quad * 4 + r;
            float v = acc[j][r] + bias[o];
            if (tz < 2) {
                const int d = o & 63;
                __bf16* dst = (tz == 0) ? qT : kT;
                dst[((size_t)(b * NH_ + h) * N_ + n) * HD_ + d] = (__bf16)(v * sc);
            } else {
                vO[(size_t)(b * C_ + o) * N_ + n] = (__bf16)v;
            }
        }
    }
}

// ---------------- output projection GEMM + residual, 128n x 64m, fp32 out ---------
__global__ __launch_bounds__(256) void gemm_o(const float* __restrict__ Wf,
                                              const float* __restrict__ bias,
                                              const __bf16* __restrict__ INt,   // [b][n][c]
                                              const float* __restrict__ RES,    // x fp32 [b][c][n]
                                              float* __restrict__ OUT) {
    const int n0 = blockIdx.x * 128;
    const int m0 = blockIdx.y * 64;
    const int b  = blockIdx.z;
    const int tid = threadIdx.x;
    const int w = tid >> 6, lane = tid & 63, quad = lane >> 4, l16 = lane & 15;

    const __bf16* inb = INt + (size_t)b * N_ * C_;
    f32x4 acc[8];
    #pragma unroll
    for (int j = 0; j < 8; j++) acc[j] = (f32x4){0.f, 0.f, 0.f, 0.f};

    const int arow = m0 + w * 16 + l16;
    const float* wrow = Wf + (size_t)arow * C_;
    #pragma unroll
    for (int kc = 0; kc < C_; kc += 32) {
        f32x4 w0 = *(const f32x4*)(wrow + kc + quad * 8);
        f32x4 w1 = *(const f32x4*)(wrow + kc + quad * 8 + 4);
        bf16x8 a;
        #pragma unroll
        for (int k = 0; k < 4; k++) { a[k] = (__bf16)w0[k]; a[4 + k] = (__bf16)w1[k]; }
        #pragma unroll
        for (int j = 0; j < 8; j++) {
            bf16x8 bfr = *(const bf16x8*)(inb + (size_t)(n0 + j * 16 + l16) * C_ + kc + quad * 8);
            acc[j] = __builtin_amdgcn_mfma_f32_16x16x32_bf16(a, bfr, acc[j], 0, 0, 0);
        }
    }
    #pragma unroll
    for (int j = 0; j < 8; j++) {
        const int n = n0 + j * 16 + l16;
        #pragma unroll
        for (int r = 0; r < 4; r++) {
            const int o = m0 + w * 16 + quad * 4 + r;
            const size_t idx = (size_t)(b * C_ + o) * N_ + n;
            OUT[idx] = acc[j][r] + bias[o] + RES[idx];
        }
    }
}

// ---------------- Flash attention (R6/R10 structure, unchanged) -------------------
__global__ __launch_bounds__(256, 2) void attn_kernel(const __bf16* __restrict__ qT,  // [16][N][64], scale*log2e folded
                                                      const __bf16* __restrict__ kT,  // [16][N][64]
                                                      const __bf16* __restrict__ V,   // [4][256][N]
                                                      __bf16* __restrict__ OT) {      // [4][N][256]
    const int flat = blockIdx.y * 32 + blockIdx.x;
    const int bh = flat & 15;          // XCD = flat%8 = bh%8 -> 2 bh per XCD (L2-resident K/V)
    const int qt = flat >> 4;          // 0..31
    const int q0 = qt * 128;
    const int b = bh >> 2, h = bh & 3;
    const int tid = threadIdx.x;
    const int w = tid >> 6, lane = tid & 63, quad = lane >> 4, l16 = lane & 15;

    __shared__ union SMem {
        struct { __bf16 K[2][64][72]; __bf16 Vt[2][64][72]; } kv;   // 36 KB dbuf
        __bf16 Ot[128][72];                                          // epilogue [q][d]
    } sm;

    const __bf16* qTb = qT + (size_t)bh * N_ * HD_;
    const __bf16* kTb = kT + (size_t)bh * N_ * HD_;
    const __bf16* Vb  = V + ((size_t)b * C_ + h * HD_) * N_;

    bf16x8 qa[2][2];
    #pragma unroll
    for (int qg = 0; qg < 2; qg++)
        #pragma unroll
        for (int kk = 0; kk < 2; kk++)
            qa[qg][kk] = *(const bf16x8*)(qTb + (size_t)(q0 + w * 32 + qg * 16 + l16) * HD_ + kk * 32 + quad * 8);

    f32x4 oacc[2][4];
    #pragma unroll
    for (int qg = 0; qg < 2; qg++)
        #pragma unroll
        for (int j = 0; j < 4; j++) oacc[qg][j] = (f32x4){0.f, 0.f, 0.f, 0.f};
    float lsum[2] = {0.f, 0.f};
    const int sl0 = ((quad & 1) * 2) * 16 + l16;
    const int sl1 = sl0 + 16;

    const int srow = tid >> 3;          // 0..31
    const int scol = (tid & 7) * 8;

    bf16x8 rk[2], rv[2];
    #pragma unroll
    for (int i = 0; i < 2; i++) {
        const int row = srow + i * 32;
        rk[i] = *(const bf16x8*)(kTb + (size_t)row * HD_ + scol);
        rv[i] = *(const bf16x8*)(Vb + (size_t)row * N_ + scol);
    }

    for (int it = 0; it < N_ / 64; it++) {
        const int cur = it & 1;
        const int nm0 = ((it + 1) * 64) & (N_ - 1);   // wraps on last (harmless reload)
        #pragma unroll
        for (int i = 0; i < 2; i++) {
            const int row = srow + i * 32;
            *(bf16x8*)(&sm.kv.K[cur][row][scol])  = rk[i];
            *(bf16x8*)(&sm.kv.Vt[cur][row][scol]) = rv[i];
        }
        #pragma unroll
        for (int i = 0; i < 2; i++) {
            const int row = srow + i * 32;
            rk[i] = *(const bf16x8*)(kTb + (size_t)(nm0 + row) * HD_ + scol);
            rv[i] = *(const bf16x8*)(Vb + (size_t)row * N_ + nm0 + scol);
        }
        __syncthreads();
        bf16x8 kb[2][4], vb[2][4];
        #pragma unroll
        for (int kk = 0; kk < 2; kk++)
            #pragma unroll
            for (int j = 0; j < 4; j++) {
                kb[kk][j] = *(const bf16x8*)(&sm.kv.K[cur][j * 16 + l16][kk * 32 + quad * 8]);
                vb[kk][j] = *(const bf16x8*)(&sm.kv.Vt[cur][j * 16 + l16][kk * 32 + quad * 8]);
            }
        #pragma unroll
        for (int qg = 0; qg < 2; qg++) {
            f32x4 s[4];
            #pragma unroll
            for (int j = 0; j < 4; j++) s[j] = (f32x4){0.f, 0.f, 0.f, 0.f};
            #pragma unroll
            for (int kk = 0; kk < 2; kk++)
                #pragma unroll
                for (int j = 0; j < 4; j++)
                    s[j] = __builtin_amdgcn_mfma_f32_16x16x32_bf16(kb[kk][j], qa[qg][kk], s[j], 0, 0, 0);
            float p[4][4];
            float ls = 0.f;
            #pragma unroll
            for (int j = 0; j < 4; j++)
                #pragma unroll
                for (int r = 0; r < 4; r++) { p[j][r] = EXP2F(s[j][r]); ls += p[j][r]; }
            lsum[qg] += ls;
            unsigned int pk0[4], pk1[4];
            #pragma unroll
            for (int j = 0; j < 4; j++) {
                pk0[j] = packbf(p[j][0], p[j][1]);
                pk1[j] = packbf(p[j][2], p[j][3]);
            }
            #pragma unroll
            for (int kk = 0; kk < 2; kk++) {
                unsigned int d0 = 0, d1 = 0, d2 = 0, d3 = 0;
                #pragma unroll
                for (int jj = 0; jj < 2; jj++) {
                    const int j = 2 * kk + jj;
                    unsigned int a0 = (unsigned int)__shfl((int)pk0[j], sl0);
                    unsigned int a1 = (unsigned int)__shfl((int)pk1[j], sl0);
                    unsigned int a2 = (unsigned int)__shfl((int)pk0[j], sl1);
                    unsigned int a3 = (unsigned int)__shfl((int)pk1[j], sl1);
                    if ((quad >> 1) == jj) { d0 = a0; d1 = a1; d2 = a2; d3 = a3; }
                }
                bf16x8 pb = __builtin_bit_cast(bf16x8, (u32x4){d0, d1, d2, d3});
                #pragma unroll
                for (int jd = 0; jd < 4; jd++)
                    oacc[qg][jd] = __builtin_amdgcn_mfma_f32_16x16x32_bf16(vb[kk][jd], pb, oacc[qg][jd], 0, 0, 0);
            }
        }
    }
    float inv[2];
    #pragma unroll
    for (int qg = 0; qg < 2; qg++) {
        float l = lsum[qg];
        l += __shfl_xor(l, 16);
        l += __shfl_xor(l, 32);
        inv[qg] = 1.f / l;
    }
    __syncthreads();
    #pragma unroll
    for (int qg = 0; qg < 2; qg++)
        #pragma unroll
        for (int jd = 0; jd < 4; jd++)
            #pragma unroll
            for (int r = 0; r < 4; r++)
                sm.Ot[w * 32 + qg * 16 + l16][jd * 16 + quad * 4 + r] = (__bf16)(oacc[qg][jd][r] * inv[qg]);
    __syncthreads();
    __bf16* Ob = OT + ((size_t)b * N_ + q0) * C_ + h * HD_;
    #pragma unroll
    for (int i = 0; i < 4; i++) {
        const int idx = tid + i * 256;
        const int row = idx >> 3, col = (idx & 7) * 8;
        *(bf16x8*)(Ob + (size_t)row * C_ + col) = *(const bf16x8*)(&sm.Ot[row][col]);
    }
}

extern "C" void kernel_launch(void* const* d_in, const int* in_sizes, int n_in,
                              void* d_out, int out_size, void* d_ws, size_t ws_size,
                              hipStream_t stream) {
    const float* x     = (const float*)d_in[0];
    const float* cond  = (const float*)d_in[1];
    const float* gnqw  = (const float*)d_in[2];
    const float* gnqb  = (const float*)d_in[3];
    const float* gnkw  = (const float*)d_in[4];
    const float* gnkb  = (const float*)d_in[5];
    const float* wq    = (const float*)d_in[6];
    const float* bq    = (const float*)d_in[7];
    const float* wk    = (const float*)d_in[8];
    const float* bk    = (const float*)d_in[9];
    const float* wv    = (const float*)d_in[10];
    const float* bv    = (const float*)d_in[11];
    const float* wo    = (const float*)d_in[12];
    const float* bo    = (const float*)d_in[13];
    float* out = (float*)d_out;

    const size_t TEN = (size_t)B_ * C_ * N_;
    __bf16* gnxT   = (__bf16*)d_ws;            // [b][n][c]
    __bf16* gncT   = gnxT + TEN;               // [b][n][c]
    __bf16* qT     = gncT + TEN;               // [bh][n][d]
    __bf16* kT     = qT  + TEN;                // [bh][n][d]
    __bf16* v      = kT  + TEN;                // [b][c][n]
    __bf16* attnoT = v   + TEN;                // [b][n][c]

    // stats (2 KB) parked in qT's space: written by gn_stats, read by gn_normT,
    // then overwritten by the qkv GEMM afterwards.
    float* stats = (float*)qT;

    gn_stats<<<dim3(2 * B_ * G_), 512, 0, stream>>>(x, cond, stats);
    gn_normT<<<dim3(1024), 256, 0, stream>>>(x, cond, gnqw, gnqb, gnkw, gnkb,
                                             stats, gnxT, gncT);

    gemm_qkv<<<dim3(N_ / 128, C_ / 64, 12), 256, 0, stream>>>(
        wq, bq, wk, bk, wv, bv, gnxT, gncT, qT, kT, v,
        0.125f * 1.44269504088896f);

    attn_kernel<<<dim3(32, 16), 256, 0, stream>>>(qT, kT, v, attnoT);

    gemm_o<<<dim3(N_ / 128, C_ / 64, B_), 256, 0, stream>>>(wo, bo, attnoT, x, out);
}